// Round 3
// baseline (3504.641 us; speedup 1.0000x reference)
//
#include <hip/hip_runtime.h>
#include <math.h>

typedef short short8 __attribute__((ext_vector_type(8)));
typedef float f32x4 __attribute__((ext_vector_type(4)));
typedef unsigned short u16;
typedef unsigned int u32;

#define GAS(p) ((__attribute__((address_space(1))) void*)(p))
#define LAS(p) ((__attribute__((address_space(3))) void*)(p))

namespace {

constexpr int HW   = 1440;           // 18*80
constexpr int PBAT = 20 * 82 * 1024; // padded per-batch elems

__device__ __forceinline__ u16 f2bf(float f) {
  u32 u = __float_as_uint(f);
  return (u16)((u + 0x7FFFu + ((u >> 16) & 1u)) >> 16);
}
__device__ __forceinline__ float bf2f(u16 h) {
  return __uint_as_float(((u32)h) << 16);
}

// ---------------- NCHW fp32 -> padded NHWC bf16 ----------------
__global__ __launch_bounds__(256)
void transpose_feat(const float* __restrict__ src, u16* __restrict__ dst) {
  __shared__ float tile[128][17];
  const int bh = blockIdx.y;            // 0..143
  const int b = bh / 18, h = bh % 18;
  const int wt = blockIdx.x % 5, ct = blockIdx.x / 5;
  const int w0 = wt * 16, c0 = ct * 128;
  const int tid = threadIdx.x;
#pragma unroll
  for (int it = 0; it < 8; ++it) {
    int idx = it * 256 + tid;
    int c = idx >> 4, w = idx & 15;
    tile[c][w] = src[((size_t)(b * 1024 + c0 + c) * 18 + h) * 80 + w0 + w];
  }
  __syncthreads();
  const int px = tid >> 4, cq = tid & 15;
  union { uint4 u; u16 s[8]; } pk;
#pragma unroll
  for (int j = 0; j < 8; ++j) pk.s[j] = f2bf(tile[cq * 8 + j][px]);
  *(uint4*)(dst + ((size_t)(b * 20 + h + 1) * 82 + (w0 + px + 1)) * 1024 + c0 + cq * 8) = pk.u;
}

// ---------------- merged weight repack: 7 tensors in one dispatch ----------------
struct RepackArgs {
  const float* src[7];
  u16* dst[7];
  int O[7];
  int start[7];   // block-range prefix; start[i]..start[i+1]
  int nseg;
};

__global__ __launch_bounds__(256)
void repack_all(RepackArgs ra) {
  int blk = blockIdx.x;
  int seg = 0;
#pragma unroll
  for (int i = 1; i < 7; ++i)
    if (i < ra.nseg && blk >= ra.start[i]) seg = i;
  const float* src = ra.src[seg];
  u16* dst = ra.dst[seg];
  const int O = ra.O[seg];
  int idx = (blk - ra.start[seg]) * 256 + threadIdx.x;
  if (idx >= O * 128) return;
  int o = idx >> 7, c8 = idx & 127;
  const float* s = src + (size_t)o * 9216 + (size_t)c8 * 72;
  float v[72];
#pragma unroll
  for (int i = 0; i < 18; ++i) {
    float4 f = *(const float4*)(s + i * 4);
    v[i * 4 + 0] = f.x; v[i * 4 + 1] = f.y; v[i * 4 + 2] = f.z; v[i * 4 + 3] = f.w;
  }
#pragma unroll
  for (int t = 0; t < 9; ++t) {
    union { uint4 u; u16 h[8]; } pk;
#pragma unroll
    for (int j = 0; j < 8; ++j) pk.h[j] = f2bf(v[j * 9 + t]);
    *(uint4*)(dst + ((size_t)t * O + o) * 1024 + c8 * 8) = pk.u;
  }
}

// ---------------- deformable bilinear sampling (device body) ----------------
__device__ __forceinline__
void sample_body(int k, int lp, int pix0, int Npc,
                 const u16* __restrict__ featP, const float* __restrict__ offp,
                 u16* __restrict__ spl, int tid) {
  const int p = pix0 + lp;
  const int c8 = tid & 15;
  int b = p / HW, hw = p - b * HW;
  int h = hw / 80, w = hw - h * 80;
  float dy = offp[p * 27 + k];
  float dx = offp[p * 27 + 9 + k];
  float ml = offp[p * 27 + 18 + k];
  float m = 1.f / (1.f + expf(-ml));
  float py = (float)(h - 1 + k / 3) + dy;
  float px = (float)(w - 1 + (k % 3)) + dx;
  float y0f = floorf(py), x0f = floorf(px);
  float wy1 = py - y0f, wx1 = px - x0f;
  float wy0 = 1.f - wy1, wx0 = 1.f - wx1;
  int y0 = (int)y0f, x0 = (int)x0f;
  int ya = min(max(y0, -1), 18),  yb = min(max(y0 + 1, -1), 18);
  int xa = min(max(x0, -1), 80),  xb = min(max(x0 + 1, -1), 80);
  const u16* base = featP + (size_t)b * PBAT;
  const u16* r00 = base + ((size_t)(ya + 1) * 82 + (xa + 1)) * 1024;
  const u16* r01 = base + ((size_t)(ya + 1) * 82 + (xb + 1)) * 1024;
  const u16* r10 = base + ((size_t)(yb + 1) * 82 + (xa + 1)) * 1024;
  const u16* r11 = base + ((size_t)(yb + 1) * 82 + (xb + 1)) * 1024;
  float w00 = wy0 * wx0 * m, w01 = wy0 * wx1 * m;
  float w10 = wy1 * wx0 * m, w11 = wy1 * wx1 * m;
  u16* dst = spl + ((size_t)k * Npc + lp) * 1024;
  for (int c = c8 * 8; c < 1024; c += 128) {
    union { uint4 u; u16 h[8]; } a, bq, cq2, d, o;
    a.u   = *(const uint4*)(r00 + c);
    bq.u  = *(const uint4*)(r01 + c);
    cq2.u = *(const uint4*)(r10 + c);
    d.u   = *(const uint4*)(r11 + c);
#pragma unroll
    for (int j = 0; j < 8; ++j) {
      float v = w00 * bf2f(a.h[j]) + w01 * bf2f(bq.h[j]) +
                w10 * bf2f(cq2.h[j]) + w11 * bf2f(d.h[j]);
      o.h[j] = f2bf(v);
    }
    *(uint4*)(dst + c) = o.u;
  }
}

__global__ __launch_bounds__(256)
void sample_standalone(const u16* __restrict__ featP, const float* __restrict__ offp,
                       u16* __restrict__ spl, int pix0, int Npc) {
  sample_body(blockIdx.y, blockIdx.x * 16 + (threadIdx.x >> 4), pix0, Npc,
              featP, offp, spl, threadIdx.x);
}

// ---------------- MFMA implicit-GEMM conv body (runtime-flagged) ----------------
// flags: 1 = planes-B, 2 = store fp32 flat [p][Co], 4 = BN, 8 = ReLU
struct Job {
  const u16* W; const u16* B;
  const float* bias; const float* bng; const float* bnb;
  void* out; int Co; int flags; int pix0; int Npc;
};

__device__ void gemm_body(const Job J, int px, int oy) {
  __shared__ __align__(16) u16 As[128 * 32];
  __shared__ __align__(16) u16 Bs[128 * 32];
  const int tid = threadIdx.x;
  const int wv = tid >> 6, lane = tid & 63;
  const int o0 = oy * 128;
  const int p0 = J.pix0 + px * 128;
  const bool planes = J.flags & 1;

  const int lr = lane >> 2;
  const int qs = (lane & 3) ^ ((lane >> 3) & 3);
  int aoff[2], boff[2];
#pragma unroll
  for (int s = 0; s < 2; ++s) {
    int r = (wv * 2 + s) * 16 + lr;
    int o = min(o0 + r, J.Co - 1);
    aoff[s] = o * 1024 + qs * 8;
    int p = p0 + r;
    if (planes) {
      boff[s] = (p - J.pix0) * 1024 + qs * 8;
    } else {
      int b = p / HW, hw = p - b * HW;
      int h = hw / 80, w = hw - h * 80;
      boff[s] = ((b * 20 + h) * 82 + w) * 1024 + qs * 8;
    }
  }
  u16* aDst = As + (wv * 2) * 512;
  u16* bDst = Bs + (wv * 2) * 512;

  const int wm = wv >> 1, wn = wv & 1;
  const int frm = lane & 15;
  const int kq = lane >> 4;
  const int sel = (kq ^ ((lane >> 1) & 3)) * 16;

  f32x4 acc[4][4];
#pragma unroll
  for (int i = 0; i < 4; ++i)
#pragma unroll
    for (int j = 0; j < 4; ++j) acc[i][j] = (f32x4)0.f;

  for (int t = 0; t < 9; ++t) {
    const u16* Wt = J.W + (size_t)t * J.Co * 1024;
    const u16* Bt = J.B + (planes ? (size_t)t * (size_t)J.Npc * 1024
                                  : (size_t)(((t / 3) * 82 + (t % 3)) * 1024));
    for (int cc = 0; cc < 1024; cc += 32) {
      __syncthreads();
#pragma unroll
      for (int s = 0; s < 2; ++s) {
        __builtin_amdgcn_global_load_lds(GAS(Wt + aoff[s] + cc), LAS(aDst + s * 512), 16, 0, 0);
        __builtin_amdgcn_global_load_lds(GAS(Bt + boff[s] + cc), LAS(bDst + s * 512), 16, 0, 0);
      }
      __syncthreads();
      uint4 af[4], bf4[4];
#pragma unroll
      for (int i = 0; i < 4; ++i) {
        af[i]  = *(const uint4*)((const char*)As + (wm * 64 + i * 16 + frm) * 64 + sel);
        bf4[i] = *(const uint4*)((const char*)Bs + (wn * 64 + i * 16 + frm) * 64 + sel);
      }
#pragma unroll
      for (int i = 0; i < 4; ++i) {
        short8 a = __builtin_bit_cast(short8, af[i]);
#pragma unroll
        for (int j = 0; j < 4; ++j) {
          short8 b = __builtin_bit_cast(short8, bf4[j]);
          acc[i][j] = __builtin_amdgcn_mfma_f32_16x16x32_bf16(a, b, acc[i][j], 0, 0, 0);
        }
      }
    }
  }

  const bool f32out = J.flags & 2;
  const bool hasbn  = J.flags & 4;
  const bool hasrelu= J.flags & 8;
  size_t obase[4];
#pragma unroll
  for (int j = 0; j < 4; ++j) {
    int pn = p0 + wn * 64 + j * 16 + frm;
    if (f32out) {
      obase[j] = (size_t)pn * J.Co;
    } else {
      int b = pn / HW, hw = pn - b * HW;
      int h = hw / 80, w = hw - h * 80;
      obase[j] = ((size_t)(b * 20 + h + 1) * 82 + (w + 1)) * 1024;
    }
  }
#pragma unroll
  for (int i = 0; i < 4; ++i) {
    int o = o0 + wm * 64 + i * 16 + kq * 4;
    float bi[4], sc[4], sh[4];
#pragma unroll
    for (int r = 0; r < 4; ++r) {
      int oc = min(o + r, J.Co - 1);
      bi[r] = J.bias[oc];
      if (hasbn) { sc[r] = J.bng[oc] * rsqrtf(1.f + 1e-5f); sh[r] = J.bnb[oc]; }
      else { sc[r] = 1.f; sh[r] = 0.f; }
    }
#pragma unroll
    for (int j = 0; j < 4; ++j) {
      float v[4];
#pragma unroll
      for (int r = 0; r < 4; ++r) {
        float x = acc[i][j][r] + bi[r];
        if (hasbn) x = x * sc[r] + sh[r];
        if (hasrelu) x = fmaxf(x, 0.f);
        v[r] = x;
      }
      if (f32out) {
        float* op = (float*)J.out;
#pragma unroll
        for (int r = 0; r < 4; ++r)
          if (o + r < J.Co) op[obase[j] + o + r] = v[r];
      } else {
        u16* op = (u16*)J.out;
        ushort4 pk;
        pk.x = f2bf(v[0]); pk.y = f2bf(v[1]); pk.z = f2bf(v[2]); pk.w = f2bf(v[3]);
        *(ushort4*)(op + obase[j] + o) = pk;
      }
    }
  }
}

// two jobs split on blockIdx.y
__global__ __launch_bounds__(256)
void gemm_dual(Job j0, Job j1, int ysplit) {
  int y = blockIdx.y;
  if (y < ysplit) gemm_body(j0, blockIdx.x, y);
  else            gemm_body(j1, blockIdx.x, y - ysplit);
}

// GEMM job co-scheduled with full-range sampler. grid.x = gemmBlocks + 6480.
__global__ __launch_bounds__(256)
void gemm_sample(Job j, const u16* __restrict__ featP, const float* __restrict__ offp,
                 u16* __restrict__ spl, int gemmBlocks) {
  int gx = blockIdx.x;
  if (gx < gemmBlocks) {
    gemm_body(j, gx % 90, gx / 90);
  } else {
    int sidx = gx - gemmBlocks;           // [0, 6480)
    int k = sidx / 720, bs = sidx % 720;
    sample_body(k, bs * 16 + (threadIdx.x >> 4), 0, 11520, featP, offp, spl, threadIdx.x);
  }
}

} // namespace

extern "C" void kernel_launch(void* const* d_in, const int* in_sizes, int n_in,
                              void* d_out, int out_size, void* d_ws, size_t ws_size,
                              hipStream_t stream) {
  const float* feat   = (const float*)d_in[0];
  const float* cls_w1 = (const float*)d_in[1];
  const float* cls_b1 = (const float*)d_in[2];
  const float* cls_w2 = (const float*)d_in[3];
  const float* cls_b2 = (const float*)d_in[4];
  const float* cls_w3 = (const float*)d_in[5];
  const float* cls_b3 = (const float*)d_in[6];
  const float* off_w  = (const float*)d_in[7];
  const float* off_b  = (const float*)d_in[8];
  const float* dcn_w  = (const float*)d_in[9];
  const float* dcn_b  = (const float*)d_in[10];
  const float* bn1_g  = (const float*)d_in[11];
  const float* bn1_b  = (const float*)d_in[12];
  const float* reg_w2 = (const float*)d_in[13];
  const float* reg_b2 = (const float*)d_in[14];
  const float* bn2_g  = (const float*)d_in[15];
  const float* bn2_b  = (const float*)d_in[16];
  const float* reg_w3 = (const float*)d_in[17];
  const float* reg_b3 = (const float*)d_in[18];
  float* outp = (float*)d_out;

  const size_t ACTB = 26869760;                // 8*20*82*1024*2 bytes
  char* wsb = (char*)d_ws;
  u16* featP = (u16*)(wsb);
  u16* bufA  = (u16*)(wsb + ACTB);
  u16* bufB  = (u16*)(wsb + 2 * ACTB);
  u16* wts   = (u16*)(wsb + 3 * ACTB);
  float* offp = (float*)(wsb + 3 * ACTB + 85432320);
  u16* spl   = (u16*)(wsb + 3 * ACTB + 85432320 + 1244160);
  const size_t BASE = 3 * ACTB + 85432320 + 1244160;   // 167,285,760
  const size_t SPLB = (size_t)9 * 11520 * 1024 * 2;    // 212,336,640

  u16* offT = wts;
  u16* w1T  = wts + 248832;
  u16* w2T  = wts + 9686016;
  u16* w3T  = wts + 19123200;
  u16* dcnT = wts + 20007936;
  u16* r2T  = wts + 29445120;
  u16* r3T  = wts + 38882304;

  dim3 blk(256);

  // single memset over the 3 contiguous padded activation buffers
  hipMemsetAsync(featP, 0, 3 * ACTB, stream);
  transpose_feat<<<dim3(40, 144), blk, 0, stream>>>(feat, featP);

  {
    RepackArgs ra;
    const float* s[7] = {off_w, cls_w1, cls_w2, cls_w3, dcn_w, reg_w2, reg_w3};
    u16* d[7] = {offT, w1T, w2T, w3T, dcnT, r2T, r3T};
    int  O[7] = {27, 1024, 1024, 96, 1024, 1024, 416};
    int acc = 0;
    for (int i = 0; i < 7; ++i) {
      ra.src[i] = s[i]; ra.dst[i] = d[i]; ra.O[i] = O[i]; ra.start[i] = acc;
      acc += (O[i] * 128 + 255) / 256;
    }
    ra.nseg = 7;
    repack_all<<<dim3(acc), blk, 0, stream>>>(ra);
  }

  // job descriptors
  Job jOff  = {offT, featP, off_b, nullptr, nullptr, offp, 27, 2, 0, 0};
  Job jCls1 = {w1T, featP, cls_b1, nullptr, nullptr, bufA, 1024, 8, 0, 0};
  Job jCls2 = {w2T, bufA, cls_b2, nullptr, nullptr, bufB, 1024, 8, 0, 0};
  Job jCls3 = {w3T, bufB, cls_b3, nullptr, nullptr, outp, 96, 2, 0, 0};
  Job jReg2 = {r2T, bufA, reg_b2, bn2_g, bn2_b, bufB, 1024, 4 | 8, 0, 0};
  Job jReg3 = {r3T, bufB, reg_b3, nullptr, nullptr, outp + 1105920, 416, 2, 0, 0};

  // D2: cls1 (y<8) + offset conv (y==8), both consume featP
  gemm_dual<<<dim3(90, 9), blk, 0, stream>>>(jCls1, jOff, 8);

  if (ws_size >= BASE + SPLB) {
    // D3: cls2 GEMM co-scheduled with full deformable sampling
    gemm_sample<<<dim3(720 + 6480), blk, 0, stream>>>(jCls2, featP, offp, spl, 720);
    // D4: dcn GEMM (planes, y<8) + cls head (y==8)
    Job jDcn = {dcnT, spl, dcn_b, bn1_g, bn1_b, bufA, 1024, 1 | 4 | 8, 0, 11520};
    gemm_dual<<<dim3(90, 9), blk, 0, stream>>>(jDcn, jCls3, 8);
  } else {
    // fallback: chunked sampling (small ws)
    gemm_dual<<<dim3(90, 8), blk, 0, stream>>>(jCls2, jCls2, 8);
    size_t avail = ws_size > BASE ? ws_size - BASE : 0;
    int tiles = (int)(avail / 2359296);
    if (tiles < 1) tiles = 1;
    if (tiles > 90) tiles = 90;
    for (int t0 = 0; t0 < 90; t0 += tiles) {
      int nt = (90 - t0) < tiles ? (90 - t0) : tiles;
      int pix0 = t0 * 128, np = nt * 128;
      sample_standalone<<<dim3(nt * 8, 9), blk, 0, stream>>>(featP, offp, spl, pix0, np);
      Job jDcn = {dcnT, spl, dcn_b, bn1_g, bn1_b, bufA, 1024, 1 | 4 | 8, pix0, np};
      gemm_dual<<<dim3(nt, 8), blk, 0, stream>>>(jDcn, jDcn, 8);
    }
    gemm_dual<<<dim3(90, 1), blk, 0, stream>>>(jCls3, jCls3, 1);
  }

  // D5: reg2 (bufA -> bufB)
  gemm_dual<<<dim3(90, 8), blk, 0, stream>>>(jReg2, jReg2, 8);
  // D6: reg3 head
  gemm_dual<<<dim3(90, 4), blk, 0, stream>>>(jReg3, jReg3, 4);
}

// Round 4
// 2158.175 us; speedup vs baseline: 1.6239x; 1.6239x over previous
//
#include <hip/hip_runtime.h>
#include <math.h>

typedef short short8 __attribute__((ext_vector_type(8)));
typedef float f32x4 __attribute__((ext_vector_type(4)));
typedef unsigned short u16;
typedef unsigned int u32;

#define GAS(p) ((__attribute__((address_space(1))) void*)(p))
#define LAS(p) ((__attribute__((address_space(3))) void*)(p))

namespace {

constexpr int HW   = 1440;           // 18*80
constexpr int PBAT = 20 * 82 * 1024; // padded per-batch elems

__device__ __forceinline__ u16 f2bf(float f) {
  u32 u = __float_as_uint(f);
  return (u16)((u + 0x7FFFu + ((u >> 16) & 1u)) >> 16);
}
__device__ __forceinline__ float bf2f(u16 h) {
  return __uint_as_float(((u32)h) << 16);
}

// ---------------- NCHW fp32 -> padded NHWC bf16 ----------------
__global__ __launch_bounds__(256)
void transpose_feat(const float* __restrict__ src, u16* __restrict__ dst) {
  __shared__ float tile[128][17];
  const int bh = blockIdx.y;            // 0..143
  const int b = bh / 18, h = bh % 18;
  const int wt = blockIdx.x % 5, ct = blockIdx.x / 5;
  const int w0 = wt * 16, c0 = ct * 128;
  const int tid = threadIdx.x;
#pragma unroll
  for (int it = 0; it < 8; ++it) {
    int idx = it * 256 + tid;
    int c = idx >> 4, w = idx & 15;
    tile[c][w] = src[((size_t)(b * 1024 + c0 + c) * 18 + h) * 80 + w0 + w];
  }
  __syncthreads();
  const int px = tid >> 4, cq = tid & 15;
  union { uint4 u; u16 s[8]; } pk;
#pragma unroll
  for (int j = 0; j < 8; ++j) pk.s[j] = f2bf(tile[cq * 8 + j][px]);
  *(uint4*)(dst + ((size_t)(b * 20 + h + 1) * 82 + (w0 + px + 1)) * 1024 + c0 + cq * 8) = pk.u;
}

// ---------------- merged weight repack: 7 tensors in one dispatch ----------------
struct RepackArgs {
  const float* src[7];
  u16* dst[7];
  int O[7];
  int start[7];
  int nseg;
};

__global__ __launch_bounds__(256)
void repack_all(RepackArgs ra) {
  int blk = blockIdx.x;
  int seg = 0;
#pragma unroll
  for (int i = 1; i < 7; ++i)
    if (i < ra.nseg && blk >= ra.start[i]) seg = i;
  const float* src = ra.src[seg];
  u16* dst = ra.dst[seg];
  const int O = ra.O[seg];
  int idx = (blk - ra.start[seg]) * 256 + threadIdx.x;
  if (idx >= O * 128) return;
  int o = idx >> 7, c8 = idx & 127;
  const float* s = src + (size_t)o * 9216 + (size_t)c8 * 72;
  float v[72];
#pragma unroll
  for (int i = 0; i < 18; ++i) {
    float4 f = *(const float4*)(s + i * 4);
    v[i * 4 + 0] = f.x; v[i * 4 + 1] = f.y; v[i * 4 + 2] = f.z; v[i * 4 + 3] = f.w;
  }
#pragma unroll
  for (int t = 0; t < 9; ++t) {
    union { uint4 u; u16 h[8]; } pk;
#pragma unroll
    for (int j = 0; j < 8; ++j) pk.h[j] = f2bf(v[j * 9 + t]);
    *(uint4*)(dst + ((size_t)t * O + o) * 1024 + c8 * 8) = pk.u;
  }
}

// ---------------- deformable bilinear sampling (device body) ----------------
__device__ __forceinline__
void sample_body(int k, int lp, int pix0, int Npc,
                 const u16* __restrict__ featP, const float* __restrict__ offp,
                 u16* __restrict__ spl, int tid) {
  const int p = pix0 + lp;
  const int c8 = tid & 15;
  int b = p / HW, hw = p - b * HW;
  int h = hw / 80, w = hw - h * 80;
  float dy = offp[p * 27 + k];
  float dx = offp[p * 27 + 9 + k];
  float ml = offp[p * 27 + 18 + k];
  float m = 1.f / (1.f + expf(-ml));
  float py = (float)(h - 1 + k / 3) + dy;
  float px = (float)(w - 1 + (k % 3)) + dx;
  float y0f = floorf(py), x0f = floorf(px);
  float wy1 = py - y0f, wx1 = px - x0f;
  float wy0 = 1.f - wy1, wx0 = 1.f - wx1;
  int y0 = (int)y0f, x0 = (int)x0f;
  int ya = min(max(y0, -1), 18),  yb = min(max(y0 + 1, -1), 18);
  int xa = min(max(x0, -1), 80),  xb = min(max(x0 + 1, -1), 80);
  const u16* base = featP + (size_t)b * PBAT;
  const u16* r00 = base + ((size_t)(ya + 1) * 82 + (xa + 1)) * 1024;
  const u16* r01 = base + ((size_t)(ya + 1) * 82 + (xb + 1)) * 1024;
  const u16* r10 = base + ((size_t)(yb + 1) * 82 + (xa + 1)) * 1024;
  const u16* r11 = base + ((size_t)(yb + 1) * 82 + (xb + 1)) * 1024;
  float w00 = wy0 * wx0 * m, w01 = wy0 * wx1 * m;
  float w10 = wy1 * wx0 * m, w11 = wy1 * wx1 * m;
  u16* dst = spl + ((size_t)k * Npc + lp) * 1024;
  for (int c = c8 * 8; c < 1024; c += 128) {
    union { uint4 u; u16 h[8]; } a, bq, cq2, d, o;
    a.u   = *(const uint4*)(r00 + c);
    bq.u  = *(const uint4*)(r01 + c);
    cq2.u = *(const uint4*)(r10 + c);
    d.u   = *(const uint4*)(r11 + c);
#pragma unroll
    for (int j = 0; j < 8; ++j) {
      float v = w00 * bf2f(a.h[j]) + w01 * bf2f(bq.h[j]) +
                w10 * bf2f(cq2.h[j]) + w11 * bf2f(d.h[j]);
      o.h[j] = f2bf(v);
    }
    *(uint4*)(dst + c) = o.u;
  }
}

__global__ __launch_bounds__(256)
void sample_standalone(const u16* __restrict__ featP, const float* __restrict__ offp,
                       u16* __restrict__ spl, int pix0, int Npc) {
  sample_body(blockIdx.y, blockIdx.x * 16 + (threadIdx.x >> 4), pix0, Npc,
              featP, offp, spl, threadIdx.x);
}

// ---------------- MFMA implicit-GEMM conv body, compile-time specialized ----------------
// FLAGS: 1 = planes-B, 2 = store fp32 flat [p][Co], 4 = BN, 8 = ReLU
struct Job {
  const u16* W; const u16* B;
  const float* bias; const float* bng; const float* bnb;
  void* out; int Co; int pix0; int Npc;
};

template<int FLAGS>
__device__ __forceinline__ void gemm_body(const Job J, int px, int oy) {
  constexpr bool PLANES  = (FLAGS & 1) != 0;
  constexpr bool F32OUT  = (FLAGS & 2) != 0;
  constexpr bool HASBN   = (FLAGS & 4) != 0;
  constexpr bool HASRELU = (FLAGS & 8) != 0;

  __shared__ __align__(16) u16 As[128 * 32];
  __shared__ __align__(16) u16 Bs[128 * 32];
  const int tid = threadIdx.x;
  const int wv = tid >> 6, lane = tid & 63;
  const int o0 = oy * 128;
  const int p0 = J.pix0 + px * 128;

  const int lr = lane >> 2;
  const int qs = (lane & 3) ^ ((lane >> 3) & 3);
  int aoff[2], boff[2];
#pragma unroll
  for (int s = 0; s < 2; ++s) {
    int r = (wv * 2 + s) * 16 + lr;
    int o = min(o0 + r, J.Co - 1);
    aoff[s] = o * 1024 + qs * 8;
    int p = p0 + r;
    if (PLANES) {
      boff[s] = (p - J.pix0) * 1024 + qs * 8;
    } else {
      int b = p / HW, hw = p - b * HW;
      int h = hw / 80, w = hw - h * 80;
      boff[s] = ((b * 20 + h) * 82 + w) * 1024 + qs * 8;
    }
  }
  u16* aDst = As + (wv * 2) * 512;
  u16* bDst = Bs + (wv * 2) * 512;

  const int wm = wv >> 1, wn = wv & 1;
  const int frm = lane & 15;
  const int kq = lane >> 4;
  const int sel = (kq ^ ((lane >> 1) & 3)) * 16;

  f32x4 acc[4][4];
#pragma unroll
  for (int i = 0; i < 4; ++i)
#pragma unroll
    for (int j = 0; j < 4; ++j) acc[i][j] = (f32x4)0.f;

  for (int t = 0; t < 9; ++t) {
    const u16* Wt = J.W + (size_t)t * J.Co * 1024;
    const u16* Bt = J.B + (PLANES ? (size_t)t * (size_t)J.Npc * 1024
                                  : (size_t)(((t / 3) * 82 + (t % 3)) * 1024));
    for (int cc = 0; cc < 1024; cc += 32) {
      __syncthreads();
#pragma unroll
      for (int s = 0; s < 2; ++s) {
        __builtin_amdgcn_global_load_lds(GAS(Wt + aoff[s] + cc), LAS(aDst + s * 512), 16, 0, 0);
        __builtin_amdgcn_global_load_lds(GAS(Bt + boff[s] + cc), LAS(bDst + s * 512), 16, 0, 0);
      }
      __syncthreads();
      uint4 af[4], bf4[4];
#pragma unroll
      for (int i = 0; i < 4; ++i) {
        af[i]  = *(const uint4*)((const char*)As + (wm * 64 + i * 16 + frm) * 64 + sel);
        bf4[i] = *(const uint4*)((const char*)Bs + (wn * 64 + i * 16 + frm) * 64 + sel);
      }
#pragma unroll
      for (int i = 0; i < 4; ++i) {
        short8 a = __builtin_bit_cast(short8, af[i]);
#pragma unroll
        for (int j = 0; j < 4; ++j) {
          short8 b = __builtin_bit_cast(short8, bf4[j]);
          acc[i][j] = __builtin_amdgcn_mfma_f32_16x16x32_bf16(a, b, acc[i][j], 0, 0, 0);
        }
      }
    }
  }

  size_t obase[4];
#pragma unroll
  for (int j = 0; j < 4; ++j) {
    int pn = p0 + wn * 64 + j * 16 + frm;
    if (F32OUT) {
      obase[j] = (size_t)pn * J.Co;
    } else {
      int b = pn / HW, hw = pn - b * HW;
      int h = hw / 80, w = hw - h * 80;
      obase[j] = ((size_t)(b * 20 + h + 1) * 82 + (w + 1)) * 1024;
    }
  }
#pragma unroll
  for (int i = 0; i < 4; ++i) {
    int o = o0 + wm * 64 + i * 16 + kq * 4;
    float bi[4], sc[4], sh[4];
#pragma unroll
    for (int r = 0; r < 4; ++r) {
      int oc = min(o + r, J.Co - 1);
      bi[r] = J.bias[oc];
      if (HASBN) { sc[r] = J.bng[oc] * rsqrtf(1.f + 1e-5f); sh[r] = J.bnb[oc]; }
    }
#pragma unroll
    for (int j = 0; j < 4; ++j) {
      float v[4];
#pragma unroll
      for (int r = 0; r < 4; ++r) {
        float x = acc[i][j][r] + bi[r];
        if (HASBN) x = x * sc[r] + sh[r];
        if (HASRELU) x = fmaxf(x, 0.f);
        v[r] = x;
      }
      if (F32OUT) {
        float* op = (float*)J.out;
#pragma unroll
        for (int r = 0; r < 4; ++r)
          if (o + r < J.Co) op[obase[j] + o + r] = v[r];
      } else {
        u16* op = (u16*)J.out;
        ushort4 pk;
        pk.x = f2bf(v[0]); pk.y = f2bf(v[1]); pk.z = f2bf(v[2]); pk.w = f2bf(v[3]);
        *(ushort4*)(op + obase[j] + o) = pk;
      }
    }
  }
}

// two jobs (compile-time specialized) split on blockIdx.y
template<int F0, int F1>
__global__ __launch_bounds__(256)
void gemm_dual(Job j0, Job j1, int ysplit) {
  int y = blockIdx.y;
  if (y < ysplit) gemm_body<F0>(j0, blockIdx.x, y);
  else            gemm_body<F1>(j1, blockIdx.x, y - ysplit);
}

// GEMM job co-scheduled with full-range sampler. grid.x = gemmBlocks + 6480.
template<int F0>
__global__ __launch_bounds__(256)
void gemm_sample(Job j, const u16* __restrict__ featP, const float* __restrict__ offp,
                 u16* __restrict__ spl, int gemmBlocks) {
  int gx = blockIdx.x;
  if (gx < gemmBlocks) {
    gemm_body<F0>(j, gx % 90, gx / 90);
  } else {
    int sidx = gx - gemmBlocks;           // [0, 6480)
    int k = sidx / 720, bs = sidx % 720;
    sample_body(k, bs * 16 + (threadIdx.x >> 4), 0, 11520, featP, offp, spl, threadIdx.x);
  }
}

} // namespace

extern "C" void kernel_launch(void* const* d_in, const int* in_sizes, int n_in,
                              void* d_out, int out_size, void* d_ws, size_t ws_size,
                              hipStream_t stream) {
  const float* feat   = (const float*)d_in[0];
  const float* cls_w1 = (const float*)d_in[1];
  const float* cls_b1 = (const float*)d_in[2];
  const float* cls_w2 = (const float*)d_in[3];
  const float* cls_b2 = (const float*)d_in[4];
  const float* cls_w3 = (const float*)d_in[5];
  const float* cls_b3 = (const float*)d_in[6];
  const float* off_w  = (const float*)d_in[7];
  const float* off_b  = (const float*)d_in[8];
  const float* dcn_w  = (const float*)d_in[9];
  const float* dcn_b  = (const float*)d_in[10];
  const float* bn1_g  = (const float*)d_in[11];
  const float* bn1_b  = (const float*)d_in[12];
  const float* reg_w2 = (const float*)d_in[13];
  const float* reg_b2 = (const float*)d_in[14];
  const float* bn2_g  = (const float*)d_in[15];
  const float* bn2_b  = (const float*)d_in[16];
  const float* reg_w3 = (const float*)d_in[17];
  const float* reg_b3 = (const float*)d_in[18];
  float* outp = (float*)d_out;

  const size_t ACTB = 26869760;                // 8*20*82*1024*2 bytes
  char* wsb = (char*)d_ws;
  u16* featP = (u16*)(wsb);
  u16* bufA  = (u16*)(wsb + ACTB);
  u16* bufB  = (u16*)(wsb + 2 * ACTB);
  u16* wts   = (u16*)(wsb + 3 * ACTB);
  float* offp = (float*)(wsb + 3 * ACTB + 85432320);
  u16* spl   = (u16*)(wsb + 3 * ACTB + 85432320 + 1244160);
  const size_t BASE = 3 * ACTB + 85432320 + 1244160;   // 167,285,760
  const size_t SPLB = (size_t)9 * 11520 * 1024 * 2;    // 212,336,640

  u16* offT = wts;
  u16* w1T  = wts + 248832;
  u16* w2T  = wts + 9686016;
  u16* w3T  = wts + 19123200;
  u16* dcnT = wts + 20007936;
  u16* r2T  = wts + 29445120;
  u16* r3T  = wts + 38882304;

  dim3 blk(256);

  hipMemsetAsync(featP, 0, 3 * ACTB, stream);
  transpose_feat<<<dim3(40, 144), blk, 0, stream>>>(feat, featP);

  {
    RepackArgs ra;
    const float* s[7] = {off_w, cls_w1, cls_w2, cls_w3, dcn_w, reg_w2, reg_w3};
    u16* d[7] = {offT, w1T, w2T, w3T, dcnT, r2T, r3T};
    int  O[7] = {27, 1024, 1024, 96, 1024, 1024, 416};
    int acc = 0;
    for (int i = 0; i < 7; ++i) {
      ra.src[i] = s[i]; ra.dst[i] = d[i]; ra.O[i] = O[i]; ra.start[i] = acc;
      acc += (O[i] * 128 + 255) / 256;
    }
    ra.nseg = 7;
    repack_all<<<dim3(acc), blk, 0, stream>>>(ra);
  }

  Job jOff  = {offT, featP, off_b, nullptr, nullptr, offp, 27, 0, 0};
  Job jCls1 = {w1T, featP, cls_b1, nullptr, nullptr, bufA, 1024, 0, 0};
  Job jCls2 = {w2T, bufA, cls_b2, nullptr, nullptr, bufB, 1024, 0, 0};
  Job jCls3 = {w3T, bufB, cls_b3, nullptr, nullptr, outp, 96, 0, 0};
  Job jReg2 = {r2T, bufA, reg_b2, bn2_g, bn2_b, bufB, 1024, 0, 0};
  Job jReg3 = {r3T, bufB, reg_b3, nullptr, nullptr, outp + 1105920, 416, 0, 0};

  // D2: cls1 (relu->bf16, y<8) + offset conv (f32 flat, y==8)
  gemm_dual<8, 2><<<dim3(90, 9), blk, 0, stream>>>(jCls1, jOff, 8);

  if (ws_size >= BASE + SPLB) {
    // D3: cls2 GEMM co-scheduled with full deformable sampling
    gemm_sample<8><<<dim3(720 + 6480), blk, 0, stream>>>(jCls2, featP, offp, spl, 720);
    // D4: dcn GEMM (planes+bn+relu, y<8) + cls head (f32, y==8)
    Job jDcn = {dcnT, spl, dcn_b, bn1_g, bn1_b, bufA, 1024, 0, 11520};
    gemm_dual<1 | 4 | 8, 2><<<dim3(90, 9), blk, 0, stream>>>(jDcn, jCls3, 8);
  } else {
    gemm_dual<8, 8><<<dim3(90, 8), blk, 0, stream>>>(jCls2, jCls2, 8);
    size_t avail = ws_size > BASE ? ws_size - BASE : 0;
    int tiles = (int)(avail / 2359296);
    if (tiles < 1) tiles = 1;
    if (tiles > 90) tiles = 90;
    for (int t0 = 0; t0 < 90; t0 += tiles) {
      int nt = (90 - t0) < tiles ? (90 - t0) : tiles;
      int pix0 = t0 * 128, np = nt * 128;
      sample_standalone<<<dim3(nt * 8, 9), blk, 0, stream>>>(featP, offp, spl, pix0, np);
      Job jDcn = {dcnT, spl, dcn_b, bn1_g, bn1_b, bufA, 1024, pix0, np};
      gemm_dual<1 | 4 | 8, 1 | 4 | 8><<<dim3(nt, 8), blk, 0, stream>>>(jDcn, jDcn, 8);
    }
    gemm_dual<2, 2><<<dim3(90, 1), blk, 0, stream>>>(jCls3, jCls3, 1);
  }

  // D5: reg2 (bufA -> bufB, bn+relu)
  gemm_dual<4 | 8, 4 | 8><<<dim3(90, 8), blk, 0, stream>>>(jReg2, jReg2, 8);
  // D6: reg3 head (f32 flat)
  gemm_dual<2, 2><<<dim3(90, 4), blk, 0, stream>>>(jReg3, jReg3, 4);
}